// Round 1
// baseline (1138.016 us; speedup 1.0000x reference)
//
#include <hip/hip_runtime.h>
#include <hip/hip_bf16.h>

#define T_TOK 8192
#define DIM   1024
#define HID   4096
#define NE    8
#define RCAP  (T_TOK * 2 + 128)

typedef unsigned short u16;
typedef unsigned int   u32;
typedef float  f32x4 __attribute__((ext_vector_type(4)));
typedef __bf16 bf16x8 __attribute__((ext_vector_type(8)));

__device__ __forceinline__ u16 f2bf(float f) {
    u32 u = __builtin_bit_cast(u32, f);
    return (u16)((u + 0x7FFFu + ((u >> 16) & 1u)) >> 16);
}

#define GLOAD_LDS16(g, l) \
    __builtin_amdgcn_global_load_lds((const __attribute__((address_space(1))) u32*)(g), \
                                     (__attribute__((address_space(3))) u32*)(l), 16, 0, 0)

// ---------------- router: one wave per token ----------------
__global__ __launch_bounds__(256) void router_kernel(
    const float* __restrict__ x, const float* __restrict__ gw,
    int* __restrict__ tok_e, float* __restrict__ tok_w, int* __restrict__ cnt)
{
    int wid  = threadIdx.x >> 6;
    int lane = threadIdx.x & 63;
    int t = blockIdx.x * 4 + wid;

    const float4* xp = (const float4*)(x + (size_t)t * DIM);
    float4 xv[4];
    #pragma unroll
    for (int c = 0; c < 4; ++c) xv[c] = xp[c * 64 + lane];

    float r[NE];
    #pragma unroll
    for (int e = 0; e < NE; ++e) {
        const float4* gp = (const float4*)(gw + e * DIM);
        float acc = 0.f;
        #pragma unroll
        for (int c = 0; c < 4; ++c) {
            float4 g = gp[c * 64 + lane];
            acc += xv[c].x * g.x + xv[c].y * g.y + xv[c].z * g.z + xv[c].w * g.w;
        }
        r[e] = acc;
    }
    #pragma unroll
    for (int s = 1; s < 64; s <<= 1) {
        #pragma unroll
        for (int e = 0; e < NE; ++e) r[e] += __shfl_xor(r[e], s);
    }
    if (lane == 0) {
        int e0 = 0; float l0 = r[0];
        #pragma unroll
        for (int e = 1; e < NE; ++e) if (r[e] > l0) { l0 = r[e]; e0 = e; }
        int e1 = -1; float l1 = -3e38f;
        #pragma unroll
        for (int e = 0; e < NE; ++e) if (e != e0 && r[e] > l1) { l1 = r[e]; e1 = e; }
        float d  = __expf(l1 - l0);          // <= 1
        float w0 = 1.f / (1.f + d);
        float w1 = d * w0;
        tok_e[t * 2]     = e0;  tok_e[t * 2 + 1] = e1;
        tok_w[t * 2]     = w0;  tok_w[t * 2 + 1] = w1;
        atomicAdd(&cnt[e0], 1);
        atomicAdd(&cnt[e1], 1);
    }
}

// ---------------- prefix sum over 8 counts ----------------
__global__ void prefix_kernel(const int* __restrict__ cnt, int* __restrict__ base)
{
    if (threadIdx.x == 0) {
        int s = 0;
        for (int e = 0; e < NE; ++e) { base[e] = s; s += cnt[e]; }
    }
}

// ---------------- scatter rows + gather x -> bf16 A1 ----------------
__global__ __launch_bounds__(256) void scatter_kernel(
    const float* __restrict__ x, const int* __restrict__ tok_e, const float* __restrict__ tok_w,
    const int* __restrict__ base, int* __restrict__ cursor,
    int* __restrict__ rowmap, float* __restrict__ roww, u16* __restrict__ A1)
{
    __shared__ int srow[2];
    int t = blockIdx.x;
    if (threadIdx.x == 0) {
        #pragma unroll
        for (int k = 0; k < 2; ++k) {
            int e   = tok_e[t * 2 + k];
            int pos = atomicAdd(&cursor[e], 1);
            int row = base[e] + pos;
            rowmap[row] = t;
            roww[row]   = tok_w[t * 2 + k];
            srow[k] = row;
        }
    }
    __syncthreads();
    int i = threadIdx.x;
    float4 xv = ((const float4*)(x + (size_t)t * DIM))[i];
    u32 p0 = (u32)f2bf(xv.x) | ((u32)f2bf(xv.y) << 16);
    u32 p1 = (u32)f2bf(xv.z) | ((u32)f2bf(xv.w) << 16);
    #pragma unroll
    for (int k = 0; k < 2; ++k) {
        u32* dst = (u32*)(A1 + (size_t)srow[k] * DIM + i * 4);
        dst[0] = p0; dst[1] = p1;
    }
}

// ---------------- fp32 -> bf16 weight conversion ----------------
__global__ __launch_bounds__(256) void convw_kernel(
    const float* __restrict__ W1, const float* __restrict__ W2,
    u16* __restrict__ W1b, u16* __restrict__ W2b)
{
    const size_t n4 = (size_t)NE * HID * DIM / 4;   // float4s per tensor
    size_t stride = (size_t)gridDim.x * blockDim.x;
    for (size_t i = blockIdx.x * (size_t)blockDim.x + threadIdx.x; i < 2 * n4; i += stride) {
        const float* src = (i < n4) ? W1 : W2;
        u16*         dst = (i < n4) ? W1b : W2b;
        size_t j = (i < n4) ? i : i - n4;
        float4 v = ((const float4*)src)[j];
        u32 p0 = (u32)f2bf(v.x) | ((u32)f2bf(v.y) << 16);
        u32 p1 = (u32)f2bf(v.z) | ((u32)f2bf(v.w) << 16);
        ((u32*)dst)[j * 2]     = p0;
        ((u32*)dst)[j * 2 + 1] = p1;
    }
}

// ---------------- grouped GEMM (128x128 tile, BK=64, 4 waves) ----------------
template<int KDIM, int NDIM, bool IS_G2>
__global__ __launch_bounds__(256) void moe_gemm(
    const u16* __restrict__ A, const u16* __restrict__ B,
    const float* __restrict__ bias,
    u16* __restrict__ Hout, float* __restrict__ Yout,
    const int* __restrict__ rowmap, const float* __restrict__ roww,
    const int* __restrict__ cnt, const int* __restrict__ base)
{
    constexpr int NT = NDIM / 128;
    constexpr int MT = 64;                 // worst case: all 8192 tokens on one expert
    int bid = blockIdx.x;
    int e   = bid / (MT * NT);
    int rem = bid % (MT * NT);
    int mt  = rem / NT;
    int nt  = rem % NT;
    int ce  = cnt[e];
    if (mt * 128 >= ce) return;
    int m0 = base[e] + mt * 128;
    int n0 = nt * 128;
    const u16* Bp = B + (size_t)e * NDIM * KDIM;

    __shared__ u16 As[128 * 64];
    __shared__ u16 Bs[128 * 64];

    int tid  = threadIdx.x;
    int lane = tid & 63;
    int w    = tid >> 6;
    int wr   = w >> 1, wc = w & 1;

    f32x4 acc[4][4];
    #pragma unroll
    for (int m = 0; m < 4; ++m)
        #pragma unroll
        for (int n = 0; n < 4; ++n)
            #pragma unroll
            for (int i = 0; i < 4; ++i) acc[m][n][i] = 0.f;

    int rsub = lane >> 3;            // 0..7
    int cel  = (lane & 7) * 8;       // element column within 64-wide K tile

    for (int kt = 0; kt < KDIM / 64; ++kt) {
        #pragma unroll
        for (int j = 0; j < 4; ++j) {
            int c = w * 4 + j;               // chunk 0..15, 8 rows each
            int r = c * 8 + rsub;
            const u16* ga = A  + (size_t)(m0 + r) * KDIM + kt * 64 + cel;
            const u16* gb = Bp + (size_t)(n0 + r) * KDIM + kt * 64 + cel;
            GLOAD_LDS16(ga, As + c * 512);
            GLOAD_LDS16(gb, Bs + c * 512);
        }
        __syncthreads();
        #pragma unroll
        for (int kk = 0; kk < 2; ++kk) {
            bf16x8 af[4], bfr[4];
            #pragma unroll
            for (int m = 0; m < 4; ++m)
                af[m] = *(const bf16x8*)(As + (wr * 64 + m * 16 + (lane & 15)) * 64 + kk * 32 + (lane >> 4) * 8);
            #pragma unroll
            for (int n = 0; n < 4; ++n)
                bfr[n] = *(const bf16x8*)(Bs + (wc * 64 + n * 16 + (lane & 15)) * 64 + kk * 32 + (lane >> 4) * 8);
            #pragma unroll
            for (int m = 0; m < 4; ++m)
                #pragma unroll
                for (int n = 0; n < 4; ++n)
                    acc[m][n] = __builtin_amdgcn_mfma_f32_16x16x32_bf16(af[m], bfr[n], acc[m][n], 0, 0, 0);
        }
        __syncthreads();
    }

    // epilogue: C/D layout col = lane&15, row = (lane>>4)*4 + reg (m89-verified)
    #pragma unroll
    for (int m = 0; m < 4; ++m) {
        #pragma unroll
        for (int j = 0; j < 4; ++j) {
            int rr   = wr * 64 + m * 16 + (lane >> 4) * 4 + j;
            int rloc = mt * 128 + rr;
            if (rloc < ce) {
                if (!IS_G2) {
                    u16* hp = Hout + (size_t)(m0 + rr) * NDIM;
                    #pragma unroll
                    for (int n = 0; n < 4; ++n) {
                        int gcol = n0 + wc * 64 + n * 16 + (lane & 15);
                        float v = acc[m][n][j] + bias[e * NDIM + gcol];
                        v = v > 0.f ? v : 0.f;
                        hp[gcol] = f2bf(v);
                    }
                } else {
                    int   tok = rowmap[m0 + rr];
                    float wgt = roww[m0 + rr];
                    float* op = Yout + (size_t)tok * DIM;
                    #pragma unroll
                    for (int n = 0; n < 4; ++n) {
                        int gcol = n0 + wc * 64 + n * 16 + (lane & 15);
                        float v = acc[m][n][j] + bias[e * NDIM + gcol];
                        atomicAdd(op + gcol, wgt * v);
                    }
                }
            }
        }
    }
}

extern "C" void kernel_launch(void* const* d_in, const int* in_sizes, int n_in,
                              void* d_out, int out_size, void* d_ws, size_t ws_size,
                              hipStream_t stream) {
    const float* xs = (const float*)d_in[0];
    const float* gw = (const float*)d_in[1];
    const float* W1 = (const float*)d_in[2];
    const float* b1 = (const float*)d_in[3];
    const float* W2 = (const float*)d_in[4];
    const float* b2 = (const float*)d_in[5];
    float* out = (float*)d_out;

    char* ws = (char*)d_ws;
    size_t off = 0;
    auto alloc = [&](size_t bytes) -> void* {
        off = (off + 255) & ~(size_t)255;
        void* p = ws + off;
        off += bytes;
        return p;
    };
    int*   ctrs   = (int*)alloc(64);            // cnt[8] + cursor[8]
    int*   cnt    = ctrs;
    int*   cursor = ctrs + 8;
    int*   base   = (int*)alloc(32);
    int*   tok_e  = (int*)alloc((size_t)T_TOK * 2 * 4);
    float* tok_w  = (float*)alloc((size_t)T_TOK * 2 * 4);
    int*   rowmap = (int*)alloc((size_t)RCAP * 4);
    float* roww   = (float*)alloc((size_t)RCAP * 4);
    u16*   A1     = (u16*)alloc((size_t)RCAP * DIM * 2);
    u16*   W1b    = (u16*)alloc((size_t)NE * HID * DIM * 2);
    u16*   W2b    = (u16*)alloc((size_t)NE * HID * DIM * 2);
    u16*   hbuf   = (u16*)alloc((size_t)RCAP * HID * 2);
    (void)ws_size; (void)in_sizes; (void)n_in; (void)out_size;

    hipMemsetAsync(out, 0, (size_t)T_TOK * DIM * sizeof(float), stream);
    hipMemsetAsync(ctrs, 0, 64, stream);

    router_kernel<<<T_TOK / 4, 256, 0, stream>>>(xs, gw, tok_e, tok_w, cnt);
    prefix_kernel<<<1, 64, 0, stream>>>(cnt, base);
    scatter_kernel<<<T_TOK, 256, 0, stream>>>(xs, tok_e, tok_w, base, cursor, rowmap, roww, A1);
    convw_kernel<<<2048, 256, 0, stream>>>(W1, W2, W1b, W2b);

    moe_gemm<DIM, HID, false><<<NE * 64 * (HID / 128), 256, 0, stream>>>(
        A1, W1b, b1, hbuf, nullptr, nullptr, nullptr, cnt, base);
    moe_gemm<HID, DIM, true><<<NE * 64 * (DIM / 128), 256, 0, stream>>>(
        hbuf, W2b, b2, nullptr, out, rowmap, roww, cnt, base);
}